// Round 1
// baseline (178.405 us; speedup 1.0000x reference)
//
#include <hip/hip_runtime.h>

// Segmented CRF forward (OneCrfCCKSDecoder), exp-domain formulation.
// T=128, B=512, E=128, EVENTLEN=8, NEG=-10000.
//
// Per batch b: state fv[j] = M + log u[j].
// Update step t (t%8 != 0):
//   u_new[j] = sum_k (u[k] * exp(feat[t,b,k])) * exp(T[j,k])
// Renormalize u by its row max every 4 steps (t%4==3 produce, t%4==0 consume)
// to stay inside fp32 range (worst-case growth ~2.8e6 per step).
// Boundary t%8==0 (t>0) and terminal: alpha += M + log(sum_j u[j]*exp(T[E-1,j])).
// Output = sum_b alpha_b / (512*16).
//
// Layout: 256 wgs x 256 threads; wg handles 2 batches (bh = tid>>7, j = tid&127).
// exp(T[j,:]) lives in 128 VGPRs per thread; h = u*exp(feat) staged in LDS
// (double buffered, wave-uniform float4 broadcast reads in the dot).

#define NEG_VAL (-10000.0f)

__global__ __launch_bounds__(256, 1)
void crf_fwd(const float* __restrict__ feats,   // [128][512][128]
             const float* __restrict__ trans,   // [128][128]
             float* __restrict__ out)
{
    const int tid = threadIdx.x;
    const int bh  = tid >> 7;          // batch within wg: 0..1
    const int j   = tid & 127;
    const int wav = tid >> 6;          // wave id 0..3 (waves 0,1 -> bh0; 2,3 -> bh1)
    const int b   = blockIdx.x * 2 + bh;

    // Register-resident exp of transitions row j (B operand of the dot).
    float Breg[128];
    #pragma unroll
    for (int k = 0; k < 128; k += 4) {
        float4 tv = *(const float4*)(trans + j * 128 + k);
        Breg[k + 0] = __expf(tv.x);
        Breg[k + 1] = __expf(tv.y);
        Breg[k + 2] = __expf(tv.z);
        Breg[k + 3] = __expf(tv.w);
    }
    const float te = __expf(trans[127 * 128 + j]);  // exp(T[E-1, j])

    __shared__ float h_lds[2][2][128];  // [parity][bh][k]
    __shared__ float wmax[4];           // per-wave max partials
    __shared__ float wsum[4];           // per-wave sum partials

    // feat element for step t: fb[t * 65536]
    const float* fb = feats + (size_t)b * 128 + j;
    float f0 = fb[1 * 65536];   // feat[1]
    float f1 = fb[2 * 65536];   // feat[2]

    float u     = 1.0f;
    float M     = (b == 0) ? 0.0f : NEG_VAL;  // init_fv row 0 is zeroed
    float alpha = 0.0f;

    for (int t = 1; t < 128; ++t) {
        float fcur = f0;                 // feat[t] (unused on boundary steps)
        f0 = f1;
        int tp = t + 2;
        f1 = (tp < 128) ? fb[(size_t)tp * 65536] : 0.0f;  // prefetch depth 2

        if ((t & 3) == 0) {
            // consume renormalization produced at t-1 (t-1 % 4 == 3)
            __syncthreads();
            float c = fmaxf(wmax[2 * bh], wmax[2 * bh + 1]);
            u = u / c;
            M += __logf(c);              // uniform across the bh group
        }

        if ((t & 7) != 0) {
            // ---- DP update step ----
            float h = u * __expf(fcur);
            h_lds[t & 1][bh][j] = h;
            __syncthreads();

            const float4* hv = (const float4*)h_lds[t & 1][bh];
            float s0 = 0.f, s1 = 0.f, s2 = 0.f, s3 = 0.f;
            #pragma unroll
            for (int i = 0; i < 32; ++i) {
                float4 v = hv[i];
                s0 = fmaf(Breg[4 * i + 0], v.x, s0);
                s1 = fmaf(Breg[4 * i + 1], v.y, s1);
                s2 = fmaf(Breg[4 * i + 2], v.z, s2);
                s3 = fmaf(Breg[4 * i + 3], v.w, s3);
            }
            u = (s0 + s1) + (s2 + s3);

            if ((t & 3) == 3) {
                // produce renorm partials: butterfly max over the wave
                float m = u;
                #pragma unroll
                for (int off = 1; off < 64; off <<= 1)
                    m = fmaxf(m, __shfl_xor(m, off, 64));
                if ((tid & 63) == 0) wmax[wav] = m;
                // visible after the consume barrier at t+1
            }
        } else {
            // ---- event boundary: alpha accumulation (fv unchanged) ----
            float r = u * te;
            #pragma unroll
            for (int off = 1; off < 64; off <<= 1)
                r += __shfl_xor(r, off, 64);
            if ((tid & 63) == 0) wsum[wav] = r;
            __syncthreads();
            float s = wsum[2 * bh] + wsum[2 * bh + 1];
            alpha += M + __logf(s);      // uniform; only j==0 emits at the end
        }
    }

    // consume pending renorm from t=127 (127 % 4 == 3)
    __syncthreads();
    {
        float c = fmaxf(wmax[2 * bh], wmax[2 * bh + 1]);
        u = u / c;
        M += __logf(c);
    }
    // terminal accumulation
    {
        float r = u * te;
        #pragma unroll
        for (int off = 1; off < 64; off <<= 1)
            r += __shfl_xor(r, off, 64);
        if ((tid & 63) == 0) wsum[wav] = r;
        __syncthreads();
        float s = wsum[2 * bh] + wsum[2 * bh + 1];
        alpha += M + __logf(s);
    }

    if (j == 0)
        atomicAdd(out, alpha * (1.0f / (512.0f * 16.0f)));
}

extern "C" void kernel_launch(void* const* d_in, const int* in_sizes, int n_in,
                              void* d_out, int out_size, void* d_ws, size_t ws_size,
                              hipStream_t stream) {
    const float* feats = (const float*)d_in[0];   // [128,512,128] f32
    const float* trans = (const float*)d_in[1];   // [128,128] f32
    float* out = (float*)d_out;                   // scalar f32

    hipMemsetAsync(out, 0, sizeof(float), stream);
    crf_fwd<<<256, 256, 0, stream>>>(feats, trans, out);
}